// Round 5
// baseline (1573.727 us; speedup 1.0000x reference)
//
#include <hip/hip_runtime.h>

#define NN 50000
#define EE 640000
#define KPRE 320
#define AVGD 3.5f
#define EPSF 1e-5f

typedef unsigned int u32;
typedef unsigned short u16;
typedef __attribute__((ext_vector_type(8))) short short8v;  // 8 bf16 in 4 VGPRs
typedef __attribute__((ext_vector_type(4))) float f32x4;

__device__ __forceinline__ u16 f2bf(float f) {
    u32 u = __float_as_uint(f);
    u32 r = (u + 0x7fffu + ((u >> 16) & 1u)) >> 16;
    return (u16)r;
}
__device__ __forceinline__ float bf2f(u16 b) {
    return __uint_as_float(((u32)b) << 16);
}
__device__ __forceinline__ u32 pack2(float a, float b) {
    return (u32)f2bf(a) | ((u32)f2bf(b) << 16);
}

// async global(per-lane) -> LDS(uniform base + lane*16), 16B per lane
__device__ __forceinline__ void gload_lds16(const u16* g, u16* l) {
    __builtin_amdgcn_global_load_lds(
        (const __attribute__((address_space(1))) void*)g,
        (__attribute__((address_space(3))) void*)l,
        16, 0, 0);
}

// ---------------- CSR construction ----------------

__global__ void deg_kernel(const int* __restrict__ dst, int* __restrict__ deg) {
    int i = blockIdx.x * blockDim.x + threadIdx.x;
    if (i < EE) atomicAdd(&deg[dst[i]], 1);
}

__global__ void scaler_kernel(const int* __restrict__ deg,
                              float* __restrict__ amp, float* __restrict__ att) {
    int i = blockIdx.x * blockDim.x + threadIdx.x;
    if (i < NN) {
        float d = (float)deg[i];
        float logd = logf(d + 1.0f);
        amp[i] = logd / AVGD;
        att[i] = AVGD / fmaxf(logd, EPSF);
    }
}

__global__ void scan_kernel(const int* __restrict__ deg, int* __restrict__ rowstart) {
    __shared__ int wsum[16];
    int lane = threadIdx.x & 63;
    int wid = threadIdx.x >> 6;
    int carry = 0;
    if (threadIdx.x == 0) rowstart[0] = 0;
    for (int base = 0; base < NN; base += 1024) {
        int i = base + threadIdx.x;
        int v = (i < NN) ? deg[i] : 0;
        int x = v;
#pragma unroll
        for (int off = 1; off < 64; off <<= 1) {
            int y = __shfl_up(x, off, 64);
            if (lane >= off) x += y;
        }
        if (lane == 63) wsum[wid] = x;
        __syncthreads();
        if (wid == 0 && lane < 16) {
            int w = wsum[lane];
#pragma unroll
            for (int off = 1; off < 16; off <<= 1) {
                int y = __shfl_up(w, off, 64);
                if (lane >= off) w += y;
            }
            wsum[lane] = w;
        }
        __syncthreads();
        int wofs = (wid > 0) ? wsum[wid - 1] : 0;
        int total = wsum[15];
        if (i < NN) rowstart[i + 1] = carry + wofs + x;
        carry += total;
        __syncthreads();
    }
}

__global__ void fill_kernel(const int* __restrict__ dst, const int* __restrict__ rowstart,
                            int* __restrict__ cursor, int* __restrict__ eid) {
    int i = blockIdx.x * blockDim.x + threadIdx.x;
    if (i < EE) {
        int d = dst[i];
        int pos = rowstart[d] + atomicAdd(&cursor[d], 1);
        eid[pos] = i;
    }
}

__global__ void perm_idx_kernel(const int* __restrict__ eid,
                                const int* __restrict__ src, const int* __restrict__ dst,
                                int* __restrict__ psrc, int* __restrict__ pdst) {
    int p = blockIdx.x * blockDim.x + threadIdx.x;
    if (p < EE) {
        int e = eid[p];
        psrc[p] = src[e];
        pdst[p] = dst[e];
    }
}

// ---------------- converts ----------------

__global__ void cvt_h_kernel(const float* __restrict__ h, u16* __restrict__ hb) {
    int i = (blockIdx.x * blockDim.x + threadIdx.x) * 4;
    float4 v = *(const float4*)&h[i];
    uint2 p;
    p.x = pack2(v.x, v.y);
    p.y = pack2(v.z, v.w);
    *(uint2*)&hb[i] = p;
}

// ebf[p][64] = bf16(efeat[eid[p]][64])  (CSR order, layer-invariant, done once)
__global__ void cvt_ebf_kernel(const float* __restrict__ efeat, const int* __restrict__ eid,
                               u16* __restrict__ ebf) {
    int t = blockIdx.x * blockDim.x + threadIdx.x;
    int p = t >> 3, j = (t & 7) * 8;
    if (p < EE) {
        const float* ep = efeat + (size_t)eid[p] * 64 + j;
        float4 f0 = *(const float4*)ep;
        float4 f1 = *(const float4*)(ep + 4);
        uint4 o;
        o.x = pack2(f0.x, f0.y); o.y = pack2(f0.z, f0.w);
        o.z = pack2(f1.x, f1.y); o.w = pack2(f1.z, f1.w);
        *(uint4*)&ebf[(size_t)p * 64 + j] = o;
    }
}

// W[K][128] fp32 -> Wt[128][K] bf16
__global__ void cvt_wt_kernel(const float* __restrict__ W, u16* __restrict__ Wt, int K) {
    int idx = blockIdx.x * blockDim.x + threadIdx.x;
    if (idx < 128 * K) {
        int c = idx / K;
        int k = idx - c * K;
        Wt[idx] = f2bf(W[(size_t)k * 128 + c]);
    }
}

// Wp[384][640]: col c<128: postW[k][c] (W0|W1); c in 128..255: k<128 -> 0 else W2;
// c in 256..383: k<128 -> 0 else W3.
__global__ void cvt_wp_kernel(const float* __restrict__ postW, u16* __restrict__ Wp) {
    int idx = blockIdx.x * blockDim.x + threadIdx.x;
    if (idx < 384 * 640) {
        int c = idx / 640, k = idx - c * 640;
        float v;
        if (c < 128)      v = postW[(size_t)k * 128 + c];
        else if (k < 128) v = 0.f;
        else if (c < 256) v = postW[(size_t)(640 + k - 128) * 128 + (c - 128)];
        else              v = postW[(size_t)(1152 + k - 128) * 128 + (c - 256)];
        Wp[idx] = f2bf(v);
    }
}

// ---------------- Pretrans MFMA (LDS-staged, BK=64, XOR-swizzled) ----------------
// block = 128 edges x 128 cols, 4 waves each 32 edges x 128 cols (acc 2x8 f32x4).
// K = 320 in 5 chunks of 64: c0,c1 = h[psrc] cols 0-63/64-127; c2,c3 = h[pdst]; c4 = ebf.
// LDS [2][128][64] u16, linear dest; global source pre-swizzled slot' = (lane&7)^(row&7);
// ds_read applies the same XOR -> 2-way-free bank pattern. m written in CSR order.

__global__ __launch_bounds__(256, 3) void pretrans_mfma(
    const u16* __restrict__ hb, const u16* __restrict__ ebf,
    const int* __restrict__ psrc, const int* __restrict__ pdst,
    const u16* __restrict__ Wt, const float* __restrict__ bias,
    u16* __restrict__ m) {
    __shared__ u16 lds[2][128][64];   // 32 KB
    int t = threadIdx.x;
    int lane = t & 63, wid = t >> 6;
    int r = lane & 15, g = lane >> 4;
    int blockbase = blockIdx.x * 128;
    int wbase = blockbase + wid * 32;        // wave's 32 edges
    int rowsel = lane >> 3;                  // 0..7 (row within 8-row staging group)
    int slotp = ((lane & 7) ^ rowsel) * 8;   // swizzled source col slot (u16 units)

    int sidx[4], didx[4];
#pragma unroll
    for (int j = 0; j < 4; j++) {
        int e = wbase + j * 8 + rowsel;
        sidx[j] = psrc[e];
        didx[j] = pdst[e];
    }

    f32x4 acc[2][8];
#pragma unroll
    for (int es = 0; es < 2; es++)
#pragma unroll
        for (int cs = 0; cs < 8; cs++) acc[es][cs] = (f32x4)(0.f);

    auto stage = [&](int c, int buf) {
        if (c < 4) {
            int kb = (c & 1) * 64;
            const int* idx = (c < 2) ? sidx : didx;
#pragma unroll
            for (int j = 0; j < 4; j++) {
                const u16* gp = hb + (size_t)idx[j] * 128 + kb + slotp;
                gload_lds16(gp, &lds[buf][wid * 32 + j * 8][0]);
            }
        } else {
#pragma unroll
            for (int j = 0; j < 4; j++) {
                const u16* gp = ebf + (size_t)(wbase + j * 8 + rowsel) * 64 + slotp;
                gload_lds16(gp, &lds[buf][wid * 32 + j * 8][0]);
            }
        }
    };

    stage(0, 0);
#pragma unroll
    for (int c = 0; c < 5; c++) {
        __syncthreads();                 // drains stage(c); guards buf reuse
        if (c < 4) stage(c + 1, (c + 1) & 1);
#pragma unroll
        for (int kk = 0; kk < 2; kk++) {
            short8v bfr[2];
#pragma unroll
            for (int es = 0; es < 2; es++) {
                int R = wid * 32 + es * 16 + r;
                int slot = (kk * 4 + g) ^ (r & 7);
                bfr[es] = *(const short8v*)&lds[c & 1][R][slot * 8];
            }
            int kgl = c * 64 + kk * 32;
#pragma unroll
            for (int cs = 0; cs < 8; cs++) {
                short8v a = *(const short8v*)(Wt + (size_t)(cs * 16 + r) * KPRE + kgl + g * 8);
                acc[0][cs] = __builtin_amdgcn_mfma_f32_16x16x32_bf16(a, bfr[0], acc[0][cs], 0, 0, 0);
                acc[1][cs] = __builtin_amdgcn_mfma_f32_16x16x32_bf16(a, bfr[1], acc[1][cs], 0, 0, 0);
            }
        }
    }

    // D: edge = es*16 + r, col = cs*16 + g*4 + reg
#pragma unroll
    for (int cs = 0; cs < 8; cs++) {
        int c0 = cs * 16 + g * 4;
        float4 bi = *(const float4*)&bias[c0];
#pragma unroll
        for (int es = 0; es < 2; es++) {
            size_t gedge = (size_t)wbase + es * 16 + r;
            uint2 p;
            p.x = pack2(acc[es][cs][0] + bi.x, acc[es][cs][1] + bi.y);
            p.y = pack2(acc[es][cs][2] + bi.z, acc[es][cs][3] + bi.w);
            *(uint2*)&m[gedge * 128 + c0] = p;
        }
    }
}

// ---------------- Aggregation: one wave per node, sequential m rows ----------------
// writes aggb[N,512] bf16 = [mean | max | min | std]  (UNscaled; post applies amp/att)

__global__ __launch_bounds__(256) void agg_kernel(
    const u16* __restrict__ m, const int* __restrict__ rowstart,
    u16* __restrict__ aggb) {
    int w = blockIdx.x * 4 + (threadIdx.x >> 6);
    if (w >= NN) return;
    int lane = threadIdx.x & 63;
    int beg = rowstart[w], end = rowstart[w + 1];
    float s0 = 0.f, s1 = 0.f, q0 = 0.f, q1 = 0.f;
    float mx0 = -3.402823e38f, mx1 = -3.402823e38f;
    float mn0 = 3.402823e38f, mn1 = 3.402823e38f;
    for (int p = beg; p < end; p++) {
        u32 pk = *(const u32*)&m[(size_t)p * 128 + 2 * lane];
        float v0 = bf2f((u16)(pk & 0xffffu));
        float v1 = bf2f((u16)(pk >> 16));
        s0 += v0; s1 += v1;
        q0 += v0 * v0; q1 += v1 * v1;
        mx0 = fmaxf(mx0, v0); mx1 = fmaxf(mx1, v1);
        mn0 = fminf(mn0, v0); mn1 = fminf(mn1, v1);
    }
    int d = end - beg;
    size_t base = (size_t)w * 512 + 2 * lane;
    if (d > 0) {
        float inv = 1.0f / (float)d;
        float me0 = s0 * inv, me1 = s1 * inv;
        float sd0 = sqrtf(fmaxf(q0 * inv - me0 * me0, 0.f) + EPSF);
        float sd1 = sqrtf(fmaxf(q1 * inv - me1 * me1, 0.f) + EPSF);
        *(u32*)&aggb[base + 0]   = pack2(me0, me1);
        *(u32*)&aggb[base + 128] = pack2(mx0, mx1);
        *(u32*)&aggb[base + 256] = pack2(mn0, mn1);
        *(u32*)&aggb[base + 384] = pack2(sd0, sd1);
    } else {
        *(u32*)&aggb[base + 0]   = 0u;
        *(u32*)&aggb[base + 128] = 0u;
        *(u32*)&aggb[base + 256] = 0u;
        *(u32*)&aggb[base + 384] = 0u;
    }
}

// ---------------- Post MFMA: C[N,384] = [hb|aggb] @ Wp; ht = C0 + amp*C1 + att*C2 + b ----------------
// wave = 16 nodes x 384 cols, acc 24 f32x4; grid 782 blocks.

__global__ __launch_bounds__(256, 3) void post_mfma(
    const u16* __restrict__ hb, const u16* __restrict__ aggb,
    const float* __restrict__ amp, const float* __restrict__ att,
    const u16* __restrict__ Wp, const float* __restrict__ bias,
    u16* __restrict__ htb) {
    int t = threadIdx.x;
    int lane = t & 63, wid = t >> 6;
    int r = lane & 15, g = lane >> 4;
    int node = blockIdx.x * 64 + wid * 16 + r;
    int nc = node < NN ? node : NN - 1;
    const u16* hrow = hb + (size_t)nc * 128;
    const u16* arow = aggb + (size_t)nc * 512;

    f32x4 acc[24];
#pragma unroll
    for (int cs = 0; cs < 24; cs++) acc[cs] = (f32x4)(0.f);

    // phase 1: k 0..127 (h part), only col-block 0 (cs 0..7)
#pragma unroll
    for (int ks = 0; ks < 4; ks++) {
        short8v b = *(const short8v*)(hrow + ks * 32 + g * 8);
#pragma unroll
        for (int cs = 0; cs < 8; cs++) {
            short8v a = *(const short8v*)(Wp + (size_t)(cs * 16 + r) * 640 + ks * 32 + g * 8);
            acc[cs] = __builtin_amdgcn_mfma_f32_16x16x32_bf16(a, b, acc[cs], 0, 0, 0);
        }
    }
    // phase 2: k 128..639 (agg part), all 24 col-blocks
#pragma unroll 2
    for (int ks = 0; ks < 16; ks++) {
        short8v b = *(const short8v*)(arow + ks * 32 + g * 8);
#pragma unroll
        for (int cs = 0; cs < 24; cs++) {
            short8v a = *(const short8v*)(Wp + (size_t)(cs * 16 + r) * 640 + 128 + ks * 32 + g * 8);
            acc[cs] = __builtin_amdgcn_mfma_f32_16x16x32_bf16(a, b, acc[cs], 0, 0, 0);
        }
    }

    if (node < NN) {
        float av = amp[node], tv = att[node];
#pragma unroll
        for (int cs = 0; cs < 8; cs++) {
            int c0 = cs * 16 + g * 4;
            float4 bi = *(const float4*)&bias[c0];
            float o0 = acc[cs][0] + av * acc[cs + 8][0] + tv * acc[cs + 16][0] + bi.x;
            float o1 = acc[cs][1] + av * acc[cs + 8][1] + tv * acc[cs + 16][1] + bi.y;
            float o2 = acc[cs][2] + av * acc[cs + 8][2] + tv * acc[cs + 16][2] + bi.z;
            float o3 = acc[cs][3] + av * acc[cs + 8][3] + tv * acc[cs + 16][3] + bi.w;
            uint2 p;
            p.x = pack2(o0, o1);
            p.y = pack2(o2, o3);
            *(uint2*)&htb[(size_t)node * 128 + c0] = p;
        }
    }
}

// ---------------- Mix MFMA + leaky_relu + residual; writes h fp32 AND hb bf16 ----------------

__global__ __launch_bounds__(256, 2) void mix_mfma(
    const u16* __restrict__ htb, const u16* __restrict__ Wt,
    const float* __restrict__ bias, float* __restrict__ h, u16* __restrict__ hb) {
    int lane = threadIdx.x & 63;
    int wid = threadIdx.x >> 6;
    int r = lane & 15;
    int g = lane >> 4;
    int node = blockIdx.x * 64 + wid * 16 + r;
    int nc = node < NN ? node : NN - 1;
    const u16* brow = htb + (size_t)nc * 128;

    f32x4 acc[8];
#pragma unroll
    for (int cs = 0; cs < 8; cs++) acc[cs] = (f32x4)(0.f);

#pragma unroll
    for (int ks = 0; ks < 4; ks++) {
        int k0 = ks * 32;
        short8v b = *(const short8v*)(brow + k0 + g * 8);
#pragma unroll
        for (int cs = 0; cs < 8; cs++) {
            short8v a = *(const short8v*)(Wt + (size_t)(cs * 16 + r) * 128 + k0 + g * 8);
            acc[cs] = __builtin_amdgcn_mfma_f32_16x16x32_bf16(a, b, acc[cs], 0, 0, 0);
        }
    }

    if (node < NN) {
#pragma unroll
        for (int cs = 0; cs < 8; cs++) {
            int c0 = cs * 16 + g * 4;
            float4 bi = *(const float4*)&bias[c0];
            float4 v;
            v.x = acc[cs][0] + bi.x; v.y = acc[cs][1] + bi.y;
            v.z = acc[cs][2] + bi.z; v.w = acc[cs][3] + bi.w;
            v.x = v.x > 0.f ? v.x : 0.01f * v.x;
            v.y = v.y > 0.f ? v.y : 0.01f * v.y;
            v.z = v.z > 0.f ? v.z : 0.01f * v.z;
            v.w = v.w > 0.f ? v.w : 0.01f * v.w;
            size_t idx = (size_t)node * 128 + c0;
            float4 old = *(const float4*)&h[idx];
            float4 nw;
            nw.x = old.x + v.x; nw.y = old.y + v.y;
            nw.z = old.z + v.z; nw.w = old.w + v.w;
            *(float4*)&h[idx] = nw;
            uint2 pb;
            pb.x = pack2(nw.x, nw.y);
            pb.y = pack2(nw.z, nw.w);
            *(uint2*)&hb[idx] = pb;
        }
    }
}

// ---------------- launch ----------------

extern "C" void kernel_launch(void* const* d_in, const int* in_sizes, int n_in,
                              void* d_out, int out_size, void* d_ws, size_t ws_size,
                              hipStream_t stream) {
    (void)in_sizes; (void)n_in; (void)out_size; (void)ws_size;
    const float* h0    = (const float*)d_in[0];
    const float* efeat = (const float*)d_in[1];
    const int* src     = (const int*)d_in[2];
    const int* dst     = (const int*)d_in[3];
    const float* preW  = (const float*)d_in[4];
    const float* preB  = (const float*)d_in[5];
    const float* postW = (const float*)d_in[6];
    const float* postB = (const float*)d_in[7];
    const float* mixW  = (const float*)d_in[8];
    const float* mixB  = (const float*)d_in[9];
    float* hcur = (float*)d_out;

    char* ws = (char*)d_ws;
    size_t off = 0;
    auto alloc = [&](size_t bytes) {
        void* p = ws + off;
        off += (bytes + 255) & ~(size_t)255;
        return p;
    };
    u16* mbuf    = (u16*)alloc((size_t)EE * 128 * 2);   // 163.84 MB (aliased by htb 12.8 MB)
    u16* ebf     = (u16*)alloc((size_t)EE * 64 * 2);    // 81.92 MB
    u16* aggb    = (u16*)alloc((size_t)NN * 512 * 2);   // 51.20 MB
    u16* hb      = (u16*)alloc((size_t)NN * 128 * 2);   // 12.80 MB
    u16* preWt   = (u16*)alloc((size_t)128 * KPRE * 2);
    u16* Wp      = (u16*)alloc((size_t)384 * 640 * 2);
    u16* mixWt   = (u16*)alloc((size_t)128 * 128 * 2);
    int* eid     = (int*)alloc((size_t)EE * 4);
    int* psrc    = (int*)alloc((size_t)EE * 4);
    int* pdst    = (int*)alloc((size_t)EE * 4);
    int* deg     = (int*)alloc((size_t)NN * 4);
    int* rowstart= (int*)alloc((size_t)(NN + 1) * 4);
    int* cursor  = (int*)alloc((size_t)NN * 4);
    float* amp   = (float*)alloc((size_t)NN * 4);
    float* att   = (float*)alloc((size_t)NN * 4);
    u16* htb     = (u16*)mbuf;   // alias: m dead after agg; htb dead before next pretrans

    hipMemsetAsync(deg, 0, (size_t)NN * 4, stream);
    hipMemsetAsync(cursor, 0, (size_t)NN * 4, stream);
    hipMemcpyAsync(hcur, h0, (size_t)NN * 128 * 4, hipMemcpyDeviceToDevice, stream);

    deg_kernel<<<(EE + 255) / 256, 256, 0, stream>>>(dst, deg);
    scaler_kernel<<<(NN + 255) / 256, 256, 0, stream>>>(deg, amp, att);
    scan_kernel<<<1, 1024, 0, stream>>>(deg, rowstart);
    fill_kernel<<<(EE + 255) / 256, 256, 0, stream>>>(dst, rowstart, cursor, eid);
    perm_idx_kernel<<<(EE + 255) / 256, 256, 0, stream>>>(eid, src, dst, psrc, pdst);
    cvt_ebf_kernel<<<(EE * 8 + 255) / 256, 256, 0, stream>>>(efeat, eid, ebf);
    cvt_h_kernel<<<(NN * 128 / 4 + 255) / 256, 256, 0, stream>>>(hcur, hb);

    for (int l = 0; l < 2; l++) {
        cvt_wt_kernel<<<(128 * KPRE + 255) / 256, 256, 0, stream>>>(
            preW + (size_t)l * KPRE * 128, preWt, KPRE);
        cvt_wp_kernel<<<(384 * 640 + 255) / 256, 256, 0, stream>>>(
            postW + (size_t)l * 1664 * 128, Wp);
        cvt_wt_kernel<<<(128 * 128 + 255) / 256, 256, 0, stream>>>(
            mixW + (size_t)l * 128 * 128, mixWt, 128);

        pretrans_mfma<<<EE / 128, 256, 0, stream>>>(
            hb, ebf, psrc, pdst, preWt, preB + (size_t)l * 128, mbuf);
        agg_kernel<<<(NN + 3) / 4, 256, 0, stream>>>(mbuf, rowstart, aggb);
        post_mfma<<<(NN + 63) / 64, 256, 0, stream>>>(
            hb, aggb, amp, att, Wp, postB + (size_t)l * 128, htb);
        mix_mfma<<<(NN + 63) / 64, 256, 0, stream>>>(
            htb, mixWt, mixB + (size_t)l * 128, hcur, hb);
    }
}

// Round 6
// 1020.148 us; speedup vs baseline: 1.5426x; 1.5426x over previous
//
#include <hip/hip_runtime.h>

#define NN 50000
#define EE 640000
#define KPRE 320
#define AVGD 3.5f
#define EPSF 1e-5f

typedef unsigned int u32;
typedef unsigned short u16;
typedef __attribute__((ext_vector_type(8))) short short8v;  // 8 bf16 in 4 VGPRs
typedef __attribute__((ext_vector_type(4))) float f32x4;

__device__ __forceinline__ u16 f2bf(float f) {
    u32 u = __float_as_uint(f);
    u32 r = (u + 0x7fffu + ((u >> 16) & 1u)) >> 16;
    return (u16)r;
}
__device__ __forceinline__ float bf2f(u16 b) {
    return __uint_as_float(((u32)b) << 16);
}
__device__ __forceinline__ u32 pack2(float a, float b) {
    return (u32)f2bf(a) | ((u32)f2bf(b) << 16);
}

// async global(per-lane) -> LDS(wave-uniform base + lane*16), 16B per lane
__device__ __forceinline__ void gload_lds16(const u16* g, u16* l) {
    __builtin_amdgcn_global_load_lds(
        (const __attribute__((address_space(1))) void*)g,
        (__attribute__((address_space(3))) void*)l,
        16, 0, 0);
}

// ---------------- CSR construction ----------------

__global__ void deg_kernel(const int* __restrict__ dst, int* __restrict__ deg) {
    int i = blockIdx.x * blockDim.x + threadIdx.x;
    if (i < EE) atomicAdd(&deg[dst[i]], 1);
}

__global__ void scaler_kernel(const int* __restrict__ deg,
                              float* __restrict__ amp, float* __restrict__ att) {
    int i = blockIdx.x * blockDim.x + threadIdx.x;
    if (i < NN) {
        float d = (float)deg[i];
        float logd = logf(d + 1.0f);
        amp[i] = logd / AVGD;
        att[i] = AVGD / fmaxf(logd, EPSF);
    }
}

__global__ void scan_kernel(const int* __restrict__ deg, int* __restrict__ rowstart) {
    __shared__ int wsum[16];
    int lane = threadIdx.x & 63;
    int wid = threadIdx.x >> 6;
    int carry = 0;
    if (threadIdx.x == 0) rowstart[0] = 0;
    for (int base = 0; base < NN; base += 1024) {
        int i = base + threadIdx.x;
        int v = (i < NN) ? deg[i] : 0;
        int x = v;
#pragma unroll
        for (int off = 1; off < 64; off <<= 1) {
            int y = __shfl_up(x, off, 64);
            if (lane >= off) x += y;
        }
        if (lane == 63) wsum[wid] = x;
        __syncthreads();
        if (wid == 0 && lane < 16) {
            int w = wsum[lane];
#pragma unroll
            for (int off = 1; off < 16; off <<= 1) {
                int y = __shfl_up(w, off, 64);
                if (lane >= off) w += y;
            }
            wsum[lane] = w;
        }
        __syncthreads();
        int wofs = (wid > 0) ? wsum[wid - 1] : 0;
        int total = wsum[15];
        if (i < NN) rowstart[i + 1] = carry + wofs + x;
        carry += total;
        __syncthreads();
    }
}

__global__ void fill_kernel(const int* __restrict__ dst, const int* __restrict__ rowstart,
                            int* __restrict__ cursor, int* __restrict__ eid) {
    int i = blockIdx.x * blockDim.x + threadIdx.x;
    if (i < EE) {
        int d = dst[i];
        int pos = rowstart[d] + atomicAdd(&cursor[d], 1);
        eid[pos] = i;
    }
}

__global__ void perm_idx_kernel(const int* __restrict__ eid,
                                const int* __restrict__ src, const int* __restrict__ dst,
                                int* __restrict__ psrc, int* __restrict__ pdst) {
    int p = blockIdx.x * blockDim.x + threadIdx.x;
    if (p < EE) {
        int e = eid[p];
        psrc[p] = src[e];
        pdst[p] = dst[e];
    }
}

// ---------------- converts ----------------

__global__ void cvt_h_kernel(const float* __restrict__ h, u16* __restrict__ hb) {
    int i = (blockIdx.x * blockDim.x + threadIdx.x) * 4;
    float4 v = *(const float4*)&h[i];
    uint2 p;
    p.x = pack2(v.x, v.y);
    p.y = pack2(v.z, v.w);
    *(uint2*)&hb[i] = p;
}

// ebf[p][64] = bf16(efeat[eid[p]][64])  (CSR order, layer-invariant, once)
__global__ void cvt_ebf_kernel(const float* __restrict__ efeat, const int* __restrict__ eid,
                               u16* __restrict__ ebf) {
    int t = blockIdx.x * blockDim.x + threadIdx.x;
    int p = t >> 3, j = (t & 7) * 8;
    if (p < EE) {
        const float* ep = efeat + (size_t)eid[p] * 64 + j;
        float4 f0 = *(const float4*)ep;
        float4 f1 = *(const float4*)(ep + 4);
        uint4 o;
        o.x = pack2(f0.x, f0.y); o.y = pack2(f0.z, f0.w);
        o.z = pack2(f1.x, f1.y); o.w = pack2(f1.z, f1.w);
        *(uint4*)&ebf[(size_t)p * 64 + j] = o;
    }
}

// W[K][128] fp32 -> Wt[128][K] bf16 (col-major)
__global__ void cvt_wt_kernel(const float* __restrict__ W, u16* __restrict__ Wt, int K) {
    int idx = blockIdx.x * blockDim.x + threadIdx.x;
    if (idx < 128 * K) {
        int c = idx / K;
        int k = idx - c * K;
        Wt[idx] = f2bf(W[(size_t)k * 128 + c]);
    }
}

// Wp[384][640] col-major: c<128: full K from postW rows 0..639 (W0|W1);
// c 128..255: k<128 zero, else postW rows 640..1151 (W2); c 256..383: rows 1152.. (W3)
__global__ void cvt_wp_kernel(const float* __restrict__ postW, u16* __restrict__ Wp) {
    int idx = blockIdx.x * blockDim.x + threadIdx.x;
    if (idx < 384 * 640) {
        int c = idx / 640, k = idx - c * 640;
        float v;
        if (c < 128)      v = postW[(size_t)k * 128 + c];
        else if (k < 128) v = 0.f;
        else if (c < 256) v = postW[(size_t)(640 + k - 128) * 128 + (c - 128)];
        else              v = postW[(size_t)(1152 + k - 128) * 128 + (c - 256)];
        Wp[idx] = f2bf(v);
    }
}

// ---------------- Pretrans MFMA: both operands via LDS, XOR-swizzled ----------------
// block = 128 edges x 128 cols, BK=32, 10 chunks; 4 waves each 64 edges x 64 cols.
// LDS [row][4 slots x 8 u16]; physical slot p holds k-slot p^(row&3) (involution).
// Stage: linear LDS dest (wave base + lane*16), inverse-swizzled global source.
// Read: ds_read_b128 at slot g^(r&3) -> 8 lanes per bank-quad = conflict-free.

__global__ __launch_bounds__(256, 4) void pretrans_mfma(
    const u16* __restrict__ hb, const u16* __restrict__ ebf,
    const int* __restrict__ psrc, const int* __restrict__ pdst,
    const u16* __restrict__ Wt, const float* __restrict__ bias,
    u16* __restrict__ m) {
    __shared__ u16 Bs[2][128][32];   // 16 KB
    __shared__ u16 As[2][128][32];   // 16 KB
    int t = threadIdx.x;
    int l = t & 63, wid = t >> 6;
    int r = l & 15, g = l >> 4;
    int wr = wid >> 1, wc = wid & 1;
    int bb = blockIdx.x * 128;

    // staging geometry: wave wid, lane l -> rows srow and srow+64, slot p=l&3
    int srow = wid * 16 + (l >> 2);
    int p = l & 3;
    int gs = (p ^ (srow & 3)) * 8;           // (srow+64)&3 == srow&3
    int ps1 = psrc[bb + srow], ps2 = psrc[bb + srow + 64];
    int pd1 = pdst[bb + srow], pd2 = pdst[bb + srow + 64];
    u16* ldsB1base[2] = { &Bs[0][wid * 16][0], &Bs[1][wid * 16][0] };
    u16* ldsA1base[2] = { &As[0][wid * 16][0], &As[1][wid * 16][0] };

    f32x4 acc[4][4];
#pragma unroll
    for (int es = 0; es < 4; es++)
#pragma unroll
        for (int cs = 0; cs < 4; cs++) acc[es][cs] = (f32x4)(0.f);

    auto stage = [&](int c, int buf) {
        const u16 *g1, *g2;
        if (c < 8) {
            int kb = (c & 3) * 32;
            int i1 = (c < 4) ? ps1 : pd1;
            int i2 = (c < 4) ? ps2 : pd2;
            g1 = hb + (size_t)i1 * 128 + kb + gs;
            g2 = hb + (size_t)i2 * 128 + kb + gs;
        } else {
            int kb = (c - 8) * 32;
            g1 = ebf + (size_t)(bb + srow) * 64 + kb + gs;
            g2 = ebf + (size_t)(bb + srow + 64) * 64 + kb + gs;
        }
        gload_lds16(g1, ldsB1base[buf]);
        gload_lds16(g2, ldsB1base[buf] + 64 * 32);
        const u16* a1 = Wt + (size_t)srow * KPRE + c * 32 + gs;
        const u16* a2 = Wt + (size_t)(srow + 64) * KPRE + c * 32 + gs;
        gload_lds16(a1, ldsA1base[buf]);
        gload_lds16(a2, ldsA1base[buf] + 64 * 32);
    };

    int sw = (g ^ (r & 3)) * 8;              // read-side swizzled slot offset (u16)
    stage(0, 0);
#pragma unroll
    for (int c = 0; c < 10; c++) {
        __syncthreads();                     // stage(c) complete; prior buf reads done
        if (c < 9) stage(c + 1, (c + 1) & 1);
        int cb = c & 1;
        short8v bfr[4], afr[4];
#pragma unroll
        for (int es = 0; es < 4; es++)
            bfr[es] = *(const short8v*)&Bs[cb][wr * 64 + es * 16 + r][sw];
#pragma unroll
        for (int cs = 0; cs < 4; cs++)
            afr[cs] = *(const short8v*)&As[cb][wc * 64 + cs * 16 + r][sw];
#pragma unroll
        for (int cs = 0; cs < 4; cs++)
#pragma unroll
            for (int es = 0; es < 4; es++)
                acc[es][cs] = __builtin_amdgcn_mfma_f32_16x16x32_bf16(afr[cs], bfr[es], acc[es][cs], 0, 0, 0);
    }

    // D: edge = wr*64 + es*16 + r, col = wc*64 + cs*16 + g*4 + reg
#pragma unroll
    for (int cs = 0; cs < 4; cs++) {
        int c0 = wc * 64 + cs * 16 + g * 4;
        float4 bi = *(const float4*)&bias[c0];
#pragma unroll
        for (int es = 0; es < 4; es++) {
            size_t gedge = (size_t)bb + wr * 64 + es * 16 + r;
            uint2 pkd;
            pkd.x = pack2(acc[es][cs][0] + bi.x, acc[es][cs][1] + bi.y);
            pkd.y = pack2(acc[es][cs][2] + bi.z, acc[es][cs][3] + bi.w);
            *(uint2*)&m[gedge * 128 + c0] = pkd;
        }
    }
}

// ---------------- Aggregation: one wave per node, sequential m rows ----------------
// writes aggb[N,512] bf16 = [mean | max | min | std] (unscaled)

__global__ __launch_bounds__(256) void agg_kernel(
    const u16* __restrict__ m, const int* __restrict__ rowstart,
    u16* __restrict__ aggb) {
    int w = blockIdx.x * 4 + (threadIdx.x >> 6);
    if (w >= NN) return;
    int lane = threadIdx.x & 63;
    int beg = rowstart[w], end = rowstart[w + 1];
    float s0 = 0.f, s1 = 0.f, q0 = 0.f, q1 = 0.f;
    float mx0 = -3.402823e38f, mx1 = -3.402823e38f;
    float mn0 = 3.402823e38f, mn1 = 3.402823e38f;
    for (int p = beg; p < end; p++) {
        u32 pk = *(const u32*)&m[(size_t)p * 128 + 2 * lane];
        float v0 = bf2f((u16)(pk & 0xffffu));
        float v1 = bf2f((u16)(pk >> 16));
        s0 += v0; s1 += v1;
        q0 += v0 * v0; q1 += v1 * v1;
        mx0 = fmaxf(mx0, v0); mx1 = fmaxf(mx1, v1);
        mn0 = fminf(mn0, v0); mn1 = fminf(mn1, v1);
    }
    int d = end - beg;
    size_t base = (size_t)w * 512 + 2 * lane;
    if (d > 0) {
        float inv = 1.0f / (float)d;
        float me0 = s0 * inv, me1 = s1 * inv;
        float sd0 = sqrtf(fmaxf(q0 * inv - me0 * me0, 0.f) + EPSF);
        float sd1 = sqrtf(fmaxf(q1 * inv - me1 * me1, 0.f) + EPSF);
        *(u32*)&aggb[base + 0]   = pack2(me0, me1);
        *(u32*)&aggb[base + 128] = pack2(mx0, mx1);
        *(u32*)&aggb[base + 256] = pack2(mn0, mn1);
        *(u32*)&aggb[base + 384] = pack2(sd0, sd1);
    } else {
        *(u32*)&aggb[base + 0]   = 0u;
        *(u32*)&aggb[base + 128] = 0u;
        *(u32*)&aggb[base + 256] = 0u;
        *(u32*)&aggb[base + 384] = 0u;
    }
}

// ---------------- Post MFMA: C[g][N,128] = [hb|aggb] @ Wp_g ; same LDS template ----------------
// grid (391, 3); group g>0 skips the zero k<128 block (starts at chunk 4).

__global__ __launch_bounds__(256, 4) void post_mfma(
    const u16* __restrict__ hb, const u16* __restrict__ aggb,
    const u16* __restrict__ Wp, float* __restrict__ C) {
    __shared__ u16 Bs[2][128][32];
    __shared__ u16 As[2][128][32];
    int t = threadIdx.x;
    int l = t & 63, wid = t >> 6;
    int r = l & 15, g = l >> 4;
    int wr = wid >> 1, wc = wid & 1;
    int nb = blockIdx.x * 128;
    int gset = blockIdx.y;

    int srow = wid * 16 + (l >> 2);
    int p = l & 3;
    int gs = (p ^ (srow & 3)) * 8;
    int n1 = nb + srow;     if (n1 >= NN) n1 = NN - 1;
    int n2 = nb + srow + 64; if (n2 >= NN) n2 = NN - 1;
    u16* ldsB1base[2] = { &Bs[0][wid * 16][0], &Bs[1][wid * 16][0] };
    u16* ldsA1base[2] = { &As[0][wid * 16][0], &As[1][wid * 16][0] };

    f32x4 acc[4][4];
#pragma unroll
    for (int es = 0; es < 4; es++)
#pragma unroll
        for (int cs = 0; cs < 4; cs++) acc[es][cs] = (f32x4)(0.f);

    auto stage = [&](int c, int buf) {
        const u16 *g1, *g2;
        if (c < 4) {
            int kb = c * 32;
            g1 = hb + (size_t)n1 * 128 + kb + gs;
            g2 = hb + (size_t)n2 * 128 + kb + gs;
        } else {
            int kb = (c - 4) * 32;
            g1 = aggb + (size_t)n1 * 512 + kb + gs;
            g2 = aggb + (size_t)n2 * 512 + kb + gs;
        }
        gload_lds16(g1, ldsB1base[buf]);
        gload_lds16(g2, ldsB1base[buf] + 64 * 32);
        const u16* a1 = Wp + (size_t)(gset * 128 + srow) * 640 + c * 32 + gs;
        const u16* a2 = Wp + (size_t)(gset * 128 + srow + 64) * 640 + c * 32 + gs;
        gload_lds16(a1, ldsA1base[buf]);
        gload_lds16(a2, ldsA1base[buf] + 64 * 32);
    };

    int sw = (g ^ (r & 3)) * 8;
    int c0s = (gset > 0) ? 4 : 0;       // skip zero k-block for amp/att groups
    stage(c0s, 0);
    for (int c = c0s; c < 20; c++) {
        __syncthreads();
        if (c < 19) stage(c + 1, (c + 1 - c0s) & 1);
        int cb = (c - c0s) & 1;
        short8v bfr[4], afr[4];
#pragma unroll
        for (int es = 0; es < 4; es++)
            bfr[es] = *(const short8v*)&Bs[cb][wr * 64 + es * 16 + r][sw];
#pragma unroll
        for (int cs = 0; cs < 4; cs++)
            afr[cs] = *(const short8v*)&As[cb][wc * 64 + cs * 16 + r][sw];
#pragma unroll
        for (int cs = 0; cs < 4; cs++)
#pragma unroll
            for (int es = 0; es < 4; es++)
                acc[es][cs] = __builtin_amdgcn_mfma_f32_16x16x32_bf16(afr[cs], bfr[es], acc[es][cs], 0, 0, 0);
    }

    float* Cg = C + (size_t)gset * NN * 128;
#pragma unroll
    for (int cs = 0; cs < 4; cs++) {
        int cc = wc * 64 + cs * 16 + g * 4;
#pragma unroll
        for (int es = 0; es < 4; es++) {
            int node = nb + wr * 64 + es * 16 + r;
            if (node < NN) {
                float4 o;
                o.x = acc[es][cs][0]; o.y = acc[es][cs][1];
                o.z = acc[es][cs][2]; o.w = acc[es][cs][3];
                *(float4*)&Cg[(size_t)node * 128 + cc] = o;
            }
        }
    }
}

// ---------------- Mix MFMA: b = bf16(C0 + amp*C1 + att*C2 + postB); + leaky + residual ----------------
// wave = 32 nodes x 128 cols; writes h fp32 AND hb bf16

__global__ __launch_bounds__(256, 3) void mix_mfma(
    const float* __restrict__ C, const float* __restrict__ amp, const float* __restrict__ att,
    const float* __restrict__ postB, const u16* __restrict__ Wt,
    const float* __restrict__ bias, float* __restrict__ h, u16* __restrict__ hb) {
    int l = threadIdx.x & 63;
    int wid = threadIdx.x >> 6;
    int r = l & 15, g = l >> 4;
    int nbase = blockIdx.x * 128 + wid * 32;
    const float* C1 = C + (size_t)NN * 128;
    const float* C2 = C + (size_t)2 * NN * 128;

    int nd[2]; float av[2], tv[2];
#pragma unroll
    for (int es = 0; es < 2; es++) {
        int n2 = nbase + es * 16 + r;
        nd[es] = n2;
        int nc = n2 < NN ? n2 : NN - 1;
        av[es] = amp[nc]; tv[es] = att[nc];
    }

    f32x4 acc[2][8];
#pragma unroll
    for (int es = 0; es < 2; es++)
#pragma unroll
        for (int cs = 0; cs < 8; cs++) acc[es][cs] = (f32x4)(0.f);

#pragma unroll
    for (int ks = 0; ks < 4; ks++) {
        int k0 = ks * 32 + g * 8;
        float4 pb0 = *(const float4*)&postB[k0];
        float4 pb1 = *(const float4*)&postB[k0 + 4];
        short8v b[2];
#pragma unroll
        for (int es = 0; es < 2; es++) {
            int nc = nd[es] < NN ? nd[es] : NN - 1;
            size_t off = (size_t)nc * 128 + k0;
            float4 x0a = *(const float4*)&C[off],  x0b = *(const float4*)&C[off + 4];
            float4 x1a = *(const float4*)&C1[off], x1b = *(const float4*)&C1[off + 4];
            float4 x2a = *(const float4*)&C2[off], x2b = *(const float4*)&C2[off + 4];
            float a2 = av[es], t2 = tv[es];
            float v0 = x0a.x + a2 * x1a.x + t2 * x2a.x + pb0.x;
            float v1 = x0a.y + a2 * x1a.y + t2 * x2a.y + pb0.y;
            float v2 = x0a.z + a2 * x1a.z + t2 * x2a.z + pb0.z;
            float v3 = x0a.w + a2 * x1a.w + t2 * x2a.w + pb0.w;
            float v4 = x0b.x + a2 * x1b.x + t2 * x2b.x + pb1.x;
            float v5 = x0b.y + a2 * x1b.y + t2 * x2b.y + pb1.y;
            float v6 = x0b.z + a2 * x1b.z + t2 * x2b.z + pb1.z;
            float v7 = x0b.w + a2 * x1b.w + t2 * x2b.w + pb1.w;
            short8v bb;
            bb[0] = (short)f2bf(v0); bb[1] = (short)f2bf(v1);
            bb[2] = (short)f2bf(v2); bb[3] = (short)f2bf(v3);
            bb[4] = (short)f2bf(v4); bb[5] = (short)f2bf(v5);
            bb[6] = (short)f2bf(v6); bb[7] = (short)f2bf(v7);
            b[es] = bb;
        }
#pragma unroll
        for (int cs = 0; cs < 8; cs++) {
            short8v a = *(const short8v*)(Wt + (size_t)(cs * 16 + r) * 128 + ks * 32 + g * 8);
            acc[0][cs] = __builtin_amdgcn_mfma_f32_16x16x32_bf16(a, b[0], acc[0][cs], 0, 0, 0);
            acc[1][cs] = __builtin_amdgcn_mfma_f32_16x16x32_bf16(a, b[1], acc[1][cs], 0, 0, 0);
        }
    }

#pragma unroll
    for (int cs = 0; cs < 8; cs++) {
        int c0 = cs * 16 + g * 4;
        float4 bi = *(const float4*)&bias[c0];
#pragma unroll
        for (int es = 0; es < 2; es++) {
            if (nd[es] < NN) {
                float4 v;
                v.x = acc[es][cs][0] + bi.x; v.y = acc[es][cs][1] + bi.y;
                v.z = acc[es][cs][2] + bi.z; v.w = acc[es][cs][3] + bi.w;
                v.x = v.x > 0.f ? v.x : 0.01f * v.x;
                v.y = v.y > 0.f ? v.y : 0.01f * v.y;
                v.z = v.z > 0.f ? v.z : 0.01f * v.z;
                v.w = v.w > 0.f ? v.w : 0.01f * v.w;
                size_t idx = (size_t)nd[es] * 128 + c0;
                float4 old = *(const float4*)&h[idx];
                float4 nw;
                nw.x = old.x + v.x; nw.y = old.y + v.y;
                nw.z = old.z + v.z; nw.w = old.w + v.w;
                *(float4*)&h[idx] = nw;
                uint2 pb;
                pb.x = pack2(nw.x, nw.y);
                pb.y = pack2(nw.z, nw.w);
                *(uint2*)&hb[idx] = pb;
            }
        }
    }
}

// ---------------- launch ----------------

extern "C" void kernel_launch(void* const* d_in, const int* in_sizes, int n_in,
                              void* d_out, int out_size, void* d_ws, size_t ws_size,
                              hipStream_t stream) {
    (void)in_sizes; (void)n_in; (void)out_size; (void)ws_size;
    const float* h0    = (const float*)d_in[0];
    const float* efeat = (const float*)d_in[1];
    const int* src     = (const int*)d_in[2];
    const int* dst     = (const int*)d_in[3];
    const float* preW  = (const float*)d_in[4];
    const float* preB  = (const float*)d_in[5];
    const float* postW = (const float*)d_in[6];
    const float* postB = (const float*)d_in[7];
    const float* mixW  = (const float*)d_in[8];
    const float* mixB  = (const float*)d_in[9];
    float* hcur = (float*)d_out;

    char* ws = (char*)d_ws;
    size_t off = 0;
    auto alloc = [&](size_t bytes) {
        void* p = ws + off;
        off += (bytes + 255) & ~(size_t)255;
        return p;
    };
    u16* mbuf    = (u16*)alloc((size_t)EE * 128 * 2);   // 163.84 MB; C fp32 (76.8 MB) aliases it
    u16* ebf     = (u16*)alloc((size_t)EE * 64 * 2);    // 81.92 MB
    u16* aggb    = (u16*)alloc((size_t)NN * 512 * 2);   // 51.20 MB
    u16* hb      = (u16*)alloc((size_t)NN * 128 * 2);   // 12.80 MB
    u16* preWt   = (u16*)alloc((size_t)128 * KPRE * 2);
    u16* Wp      = (u16*)alloc((size_t)384 * 640 * 2);
    u16* mixWt   = (u16*)alloc((size_t)128 * 128 * 2);
    int* eid     = (int*)alloc((size_t)EE * 4);
    int* psrc    = (int*)alloc((size_t)EE * 4);
    int* pdst    = (int*)alloc((size_t)EE * 4);
    int* deg     = (int*)alloc((size_t)NN * 4);
    int* rowstart= (int*)alloc((size_t)(NN + 1) * 4);
    int* cursor  = (int*)alloc((size_t)NN * 4);
    float* amp   = (float*)alloc((size_t)NN * 4);
    float* att   = (float*)alloc((size_t)NN * 4);
    float* C     = (float*)mbuf;   // alias: m dead after agg; C dead before next pretrans

    hipMemsetAsync(deg, 0, (size_t)NN * 4, stream);
    hipMemsetAsync(cursor, 0, (size_t)NN * 4, stream);
    hipMemcpyAsync(hcur, h0, (size_t)NN * 128 * 4, hipMemcpyDeviceToDevice, stream);

    deg_kernel<<<(EE + 255) / 256, 256, 0, stream>>>(dst, deg);
    scaler_kernel<<<(NN + 255) / 256, 256, 0, stream>>>(deg, amp, att);
    scan_kernel<<<1, 1024, 0, stream>>>(deg, rowstart);
    fill_kernel<<<(EE + 255) / 256, 256, 0, stream>>>(dst, rowstart, cursor, eid);
    perm_idx_kernel<<<(EE + 255) / 256, 256, 0, stream>>>(eid, src, dst, psrc, pdst);
    cvt_ebf_kernel<<<(EE * 8 + 255) / 256, 256, 0, stream>>>(efeat, eid, ebf);
    cvt_h_kernel<<<(NN * 128 / 4 + 255) / 256, 256, 0, stream>>>(hcur, hb);

    for (int l = 0; l < 2; l++) {
        cvt_wt_kernel<<<(128 * KPRE + 255) / 256, 256, 0, stream>>>(
            preW + (size_t)l * KPRE * 128, preWt, KPRE);
        cvt_wp_kernel<<<(384 * 640 + 255) / 256, 256, 0, stream>>>(
            postW + (size_t)l * 1664 * 128, Wp);
        cvt_wt_kernel<<<(128 * 128 + 255) / 256, 256, 0, stream>>>(
            mixW + (size_t)l * 128 * 128, mixWt, 128);

        pretrans_mfma<<<EE / 128, 256, 0, stream>>>(
            hb, ebf, psrc, pdst, preWt, preB + (size_t)l * 128, mbuf);
        agg_kernel<<<(NN + 3) / 4, 256, 0, stream>>>(mbuf, rowstart, aggb);
        post_mfma<<<dim3((NN + 127) / 128, 3), 256, 0, stream>>>(hb, aggb, Wp, C);
        mix_mfma<<<(NN + 127) / 128, 256, 0, stream>>>(
            C, amp, att, postB, mixWt, mixB + (size_t)l * 128, hcur, hb);
    }
}

// Round 7
// 987.658 us; speedup vs baseline: 1.5934x; 1.0329x over previous
//
#include <hip/hip_runtime.h>

#define NN 50000
#define EE 640000
#define KPRE 320
#define AVGD 3.5f
#define EPSF 1e-5f

typedef unsigned int u32;
typedef unsigned short u16;
typedef __attribute__((ext_vector_type(8))) short short8v;  // 8 bf16 in 4 VGPRs
typedef __attribute__((ext_vector_type(4))) float f32x4;

__device__ __forceinline__ u16 f2bf(float f) {
    u32 u = __float_as_uint(f);
    u32 r = (u + 0x7fffu + ((u >> 16) & 1u)) >> 16;
    return (u16)r;
}
__device__ __forceinline__ float bf2f(u16 b) {
    return __uint_as_float(((u32)b) << 16);
}
__device__ __forceinline__ u32 pack2(float a, float b) {
    return (u32)f2bf(a) | ((u32)f2bf(b) << 16);
}

// async global(per-lane) -> LDS(wave-uniform base + lane*16), 16B per lane
__device__ __forceinline__ void gload_lds16(const u16* g, u16* l) {
    __builtin_amdgcn_global_load_lds(
        (const __attribute__((address_space(1))) void*)g,
        (__attribute__((address_space(3))) void*)l,
        16, 0, 0);
}

// ---------------- CSR construction ----------------

__global__ void deg_kernel(const int* __restrict__ dst, int* __restrict__ deg) {
    int i = blockIdx.x * blockDim.x + threadIdx.x;
    if (i < EE) atomicAdd(&deg[dst[i]], 1);
}

__global__ void scaler_kernel(const int* __restrict__ deg,
                              float* __restrict__ amp, float* __restrict__ att) {
    int i = blockIdx.x * blockDim.x + threadIdx.x;
    if (i < NN) {
        float d = (float)deg[i];
        float logd = logf(d + 1.0f);
        amp[i] = logd / AVGD;
        att[i] = AVGD / fmaxf(logd, EPSF);
    }
}

__global__ void scan_kernel(const int* __restrict__ deg, int* __restrict__ rowstart) {
    __shared__ int wsum[16];
    int lane = threadIdx.x & 63;
    int wid = threadIdx.x >> 6;
    int carry = 0;
    if (threadIdx.x == 0) rowstart[0] = 0;
    for (int base = 0; base < NN; base += 1024) {
        int i = base + threadIdx.x;
        int v = (i < NN) ? deg[i] : 0;
        int x = v;
#pragma unroll
        for (int off = 1; off < 64; off <<= 1) {
            int y = __shfl_up(x, off, 64);
            if (lane >= off) x += y;
        }
        if (lane == 63) wsum[wid] = x;
        __syncthreads();
        if (wid == 0 && lane < 16) {
            int w = wsum[lane];
#pragma unroll
            for (int off = 1; off < 16; off <<= 1) {
                int y = __shfl_up(w, off, 64);
                if (lane >= off) w += y;
            }
            wsum[lane] = w;
        }
        __syncthreads();
        int wofs = (wid > 0) ? wsum[wid - 1] : 0;
        int total = wsum[15];
        if (i < NN) rowstart[i + 1] = carry + wofs + x;
        carry += total;
        __syncthreads();
    }
}

__global__ void fill_kernel(const int* __restrict__ dst, const int* __restrict__ rowstart,
                            int* __restrict__ cursor, int* __restrict__ eid) {
    int i = blockIdx.x * blockDim.x + threadIdx.x;
    if (i < EE) {
        int d = dst[i];
        int pos = rowstart[d] + atomicAdd(&cursor[d], 1);
        eid[pos] = i;
    }
}

__global__ void perm_idx_kernel(const int* __restrict__ eid,
                                const int* __restrict__ src, const int* __restrict__ dst,
                                int* __restrict__ psrc, int* __restrict__ pdst) {
    int p = blockIdx.x * blockDim.x + threadIdx.x;
    if (p < EE) {
        int e = eid[p];
        psrc[p] = src[e];
        pdst[p] = dst[e];
    }
}

// ---------------- converts ----------------

__global__ void cvt_h_kernel(const float* __restrict__ h, u16* __restrict__ hb) {
    int i = (blockIdx.x * blockDim.x + threadIdx.x) * 4;
    float4 v = *(const float4*)&h[i];
    uint2 p;
    p.x = pack2(v.x, v.y);
    p.y = pack2(v.z, v.w);
    *(uint2*)&hb[i] = p;
}

// ebf[p][64] = bf16(efeat[eid[p]][64])  (CSR order, layer-invariant, once)
__global__ void cvt_ebf_kernel(const float* __restrict__ efeat, const int* __restrict__ eid,
                               u16* __restrict__ ebf) {
    int t = blockIdx.x * blockDim.x + threadIdx.x;
    int p = t >> 3, j = (t & 7) * 8;
    if (p < EE) {
        const float* ep = efeat + (size_t)eid[p] * 64 + j;
        float4 f0 = *(const float4*)ep;
        float4 f1 = *(const float4*)(ep + 4);
        uint4 o;
        o.x = pack2(f0.x, f0.y); o.y = pack2(f0.z, f0.w);
        o.z = pack2(f1.x, f1.y); o.w = pack2(f1.z, f1.w);
        *(uint4*)&ebf[(size_t)p * 64 + j] = o;
    }
}

// W[K][128] fp32 -> Wt[128][K] bf16 (col-major)
__global__ void cvt_wt_kernel(const float* __restrict__ W, u16* __restrict__ Wt, int K) {
    int idx = blockIdx.x * blockDim.x + threadIdx.x;
    if (idx < 128 * K) {
        int c = idx / K;
        int k = idx - c * K;
        Wt[idx] = f2bf(W[(size_t)k * 128 + c]);
    }
}

// Wp[384][640] col-major: c<128: full K from postW rows 0..639 (W0|W1);
// c 128..255: k<128 zero, else postW rows 640..1151 (W2); c 256..383: rows 1152.. (W3)
__global__ void cvt_wp_kernel(const float* __restrict__ postW, u16* __restrict__ Wp) {
    int idx = blockIdx.x * blockDim.x + threadIdx.x;
    if (idx < 384 * 640) {
        int c = idx / 640, k = idx - c * 640;
        float v;
        if (c < 128)      v = postW[(size_t)k * 128 + c];
        else if (k < 128) v = 0.f;
        else if (c < 256) v = postW[(size_t)(640 + k - 128) * 128 + (c - 128)];
        else              v = postW[(size_t)(1152 + k - 128) * 128 + (c - 256)];
        Wp[idx] = f2bf(v);
    }
}

// ---------------- Pretrans MFMA: both operands via LDS, XOR-swizzled ----------------
// block = 128 edges x 128 cols, BK=32, 10 chunks; 4 waves each 64 edges x 64 cols.
// Epilogue: acc -> LDS (swizzled) -> linear full-line global stores (kills RFO/write-amp).

__global__ __launch_bounds__(256, 5) void pretrans_mfma(
    const u16* __restrict__ hb, const u16* __restrict__ ebf,
    const int* __restrict__ psrc, const int* __restrict__ pdst,
    const u16* __restrict__ Wt, const float* __restrict__ bias,
    u16* __restrict__ m) {
    __shared__ u16 smem[16384];          // 32 KB: Bs[2][128][32] | As[2][128][32]
    u16* BsP = smem;
    u16* AsP = smem + 8192;
    int t = threadIdx.x;
    int l = t & 63, wid = t >> 6;
    int r = l & 15, g = l >> 4;
    int wr = wid >> 1, wc = wid & 1;
    int bb = blockIdx.x * 128;

    int srow = wid * 16 + (l >> 2);
    int p = l & 3;
    int gs = (p ^ (srow & 3)) * 8;       // inverse-swizzled source slot
    int ps1 = psrc[bb + srow], ps2 = psrc[bb + srow + 64];
    int pd1 = pdst[bb + srow], pd2 = pdst[bb + srow + 64];

    f32x4 acc[4][4];
#pragma unroll
    for (int es = 0; es < 4; es++)
#pragma unroll
        for (int cs = 0; cs < 4; cs++) acc[es][cs] = (f32x4)(0.f);

    auto stage = [&](int c, int buf) {
        const u16 *g1, *g2;
        if (c < 8) {
            int kb = (c & 3) * 32;
            int i1 = (c < 4) ? ps1 : pd1;
            int i2 = (c < 4) ? ps2 : pd2;
            g1 = hb + (size_t)i1 * 128 + kb + gs;
            g2 = hb + (size_t)i2 * 128 + kb + gs;
        } else {
            int kb = (c - 8) * 32;
            g1 = ebf + (size_t)(bb + srow) * 64 + kb + gs;
            g2 = ebf + (size_t)(bb + srow + 64) * 64 + kb + gs;
        }
        u16* bB = &BsP[((size_t)buf * 128 + wid * 16) * 32];
        gload_lds16(g1, bB);
        gload_lds16(g2, bB + 64 * 32);
        const u16* a1 = Wt + (size_t)srow * KPRE + c * 32 + gs;
        const u16* a2 = Wt + (size_t)(srow + 64) * KPRE + c * 32 + gs;
        u16* bA = &AsP[((size_t)buf * 128 + wid * 16) * 32];
        gload_lds16(a1, bA);
        gload_lds16(a2, bA + 64 * 32);
    };

    int sw = (g ^ (r & 3)) * 8;          // read-side swizzled slot offset (u16)
    stage(0, 0);
#pragma unroll
    for (int c = 0; c < 10; c++) {
        __syncthreads();
        if (c < 9) stage(c + 1, (c + 1) & 1);
        int cb = c & 1;
        short8v bfr[4], afr[4];
#pragma unroll
        for (int es = 0; es < 4; es++)
            bfr[es] = *(const short8v*)&BsP[((size_t)cb * 128 + wr * 64 + es * 16 + r) * 32 + sw];
#pragma unroll
        for (int cs = 0; cs < 4; cs++)
            afr[cs] = *(const short8v*)&AsP[((size_t)cb * 128 + wc * 64 + cs * 16 + r) * 32 + sw];
#pragma unroll
        for (int cs = 0; cs < 4; cs++)
#pragma unroll
            for (int es = 0; es < 4; es++)
                acc[es][cs] = __builtin_amdgcn_mfma_f32_16x16x32_bf16(afr[cs], bfr[es], acc[es][cs], 0, 0, 0);
    }

    // epilogue: acc -> LDS tile (128x128 bf16, XOR-swizzled) -> linear coalesced stores
    __syncthreads();
#pragma unroll
    for (int cs = 0; cs < 4; cs++) {
        int c0 = wc * 64 + cs * 16 + g * 4;
        float4 bi = *(const float4*)&bias[c0];
#pragma unroll
        for (int es = 0; es < 4; es++) {
            int row = wr * 64 + es * 16 + r;
            int cbyte = (c0 * 2) ^ ((row & 7) << 4);
            uint2 pkd;
            pkd.x = pack2(acc[es][cs][0] + bi.x, acc[es][cs][1] + bi.y);
            pkd.y = pack2(acc[es][cs][2] + bi.z, acc[es][cs][3] + bi.w);
            *(uint2*)((char*)smem + row * 256 + cbyte) = pkd;
        }
    }
    __syncthreads();
#pragma unroll
    for (int it = 0; it < 8; it++) {
        int idx = it * 256 + t;
        int row = idx >> 4;
        int cb2 = (idx & 15) * 16;
        int swz = cb2 ^ ((row & 7) << 4);
        uint4 v = *(const uint4*)((const char*)smem + row * 256 + swz);
        *(uint4*)((char*)(m + (size_t)(bb + row) * 128) + cb2) = v;
    }
}

// ---------------- Aggregation: one wave per node, sequential m rows ----------------
// writes aggb[N,512] bf16 = [mean | max | min | std] (unscaled)

__global__ __launch_bounds__(256) void agg_kernel(
    const u16* __restrict__ m, const int* __restrict__ rowstart,
    u16* __restrict__ aggb) {
    int w = blockIdx.x * 4 + (threadIdx.x >> 6);
    if (w >= NN) return;
    int lane = threadIdx.x & 63;
    int beg = rowstart[w], end = rowstart[w + 1];
    float s0 = 0.f, s1 = 0.f, q0 = 0.f, q1 = 0.f;
    float mx0 = -3.402823e38f, mx1 = -3.402823e38f;
    float mn0 = 3.402823e38f, mn1 = 3.402823e38f;
    for (int p = beg; p < end; p++) {
        u32 pk = *(const u32*)&m[(size_t)p * 128 + 2 * lane];
        float v0 = bf2f((u16)(pk & 0xffffu));
        float v1 = bf2f((u16)(pk >> 16));
        s0 += v0; s1 += v1;
        q0 += v0 * v0; q1 += v1 * v1;
        mx0 = fmaxf(mx0, v0); mx1 = fmaxf(mx1, v1);
        mn0 = fminf(mn0, v0); mn1 = fminf(mn1, v1);
    }
    int d = end - beg;
    size_t base = (size_t)w * 512 + 2 * lane;
    if (d > 0) {
        float inv = 1.0f / (float)d;
        float me0 = s0 * inv, me1 = s1 * inv;
        float sd0 = sqrtf(fmaxf(q0 * inv - me0 * me0, 0.f) + EPSF);
        float sd1 = sqrtf(fmaxf(q1 * inv - me1 * me1, 0.f) + EPSF);
        *(u32*)&aggb[base + 0]   = pack2(me0, me1);
        *(u32*)&aggb[base + 128] = pack2(mx0, mx1);
        *(u32*)&aggb[base + 256] = pack2(mn0, mn1);
        *(u32*)&aggb[base + 384] = pack2(sd0, sd1);
    } else {
        *(u32*)&aggb[base + 0]   = 0u;
        *(u32*)&aggb[base + 128] = 0u;
        *(u32*)&aggb[base + 256] = 0u;
        *(u32*)&aggb[base + 384] = 0u;
    }
}

// ---------------- Post MFMA: Cb[g][N,128] bf16 = [hb|aggb] @ Wp_g (+postB for g=0) ----------------

__global__ __launch_bounds__(256, 5) void post_mfma(
    const u16* __restrict__ hb, const u16* __restrict__ aggb,
    const u16* __restrict__ Wp, const float* __restrict__ postB,
    u16* __restrict__ C) {
    __shared__ u16 smem[16384];
    u16* BsP = smem;
    u16* AsP = smem + 8192;
    int t = threadIdx.x;
    int l = t & 63, wid = t >> 6;
    int r = l & 15, g = l >> 4;
    int wr = wid >> 1, wc = wid & 1;
    int nb = blockIdx.x * 128;
    int gset = blockIdx.y;

    int srow = wid * 16 + (l >> 2);
    int p = l & 3;
    int gs = (p ^ (srow & 3)) * 8;
    int n1 = nb + srow;      if (n1 >= NN) n1 = NN - 1;
    int n2 = nb + srow + 64; if (n2 >= NN) n2 = NN - 1;

    f32x4 acc[4][4];
#pragma unroll
    for (int es = 0; es < 4; es++)
#pragma unroll
        for (int cs = 0; cs < 4; cs++) acc[es][cs] = (f32x4)(0.f);

    auto stage = [&](int c, int buf) {
        const u16 *g1, *g2;
        if (c < 4) {
            int kb = c * 32;
            g1 = hb + (size_t)n1 * 128 + kb + gs;
            g2 = hb + (size_t)n2 * 128 + kb + gs;
        } else {
            int kb = (c - 4) * 32;
            g1 = aggb + (size_t)n1 * 512 + kb + gs;
            g2 = aggb + (size_t)n2 * 512 + kb + gs;
        }
        u16* bB = &BsP[((size_t)buf * 128 + wid * 16) * 32];
        gload_lds16(g1, bB);
        gload_lds16(g2, bB + 64 * 32);
        const u16* a1 = Wp + (size_t)(gset * 128 + srow) * 640 + c * 32 + gs;
        const u16* a2 = Wp + (size_t)(gset * 128 + srow + 64) * 640 + c * 32 + gs;
        u16* bA = &AsP[((size_t)buf * 128 + wid * 16) * 32];
        gload_lds16(a1, bA);
        gload_lds16(a2, bA + 64 * 32);
    };

    int sw = (g ^ (r & 3)) * 8;
    int c0s = (gset > 0) ? 4 : 0;        // skip zero k-block for amp/att groups
    stage(c0s, 0);
    for (int c = c0s; c < 20; c++) {
        __syncthreads();
        if (c < 19) stage(c + 1, (c + 1 - c0s) & 1);
        int cb = (c - c0s) & 1;
        short8v bfr[4], afr[4];
#pragma unroll
        for (int es = 0; es < 4; es++)
            bfr[es] = *(const short8v*)&BsP[((size_t)cb * 128 + wr * 64 + es * 16 + r) * 32 + sw];
#pragma unroll
        for (int cs = 0; cs < 4; cs++)
            afr[cs] = *(const short8v*)&AsP[((size_t)cb * 128 + wc * 64 + cs * 16 + r) * 32 + sw];
#pragma unroll
        for (int cs = 0; cs < 4; cs++)
#pragma unroll
            for (int es = 0; es < 4; es++)
                acc[es][cs] = __builtin_amdgcn_mfma_f32_16x16x32_bf16(afr[cs], bfr[es], acc[es][cs], 0, 0, 0);
    }

    // epilogue: acc -> LDS bf16 tile -> linear coalesced stores
    __syncthreads();
#pragma unroll
    for (int cs = 0; cs < 4; cs++) {
        int c0 = wc * 64 + cs * 16 + g * 4;
        float4 bi = make_float4(0.f, 0.f, 0.f, 0.f);
        if (gset == 0) bi = *(const float4*)&postB[c0];
#pragma unroll
        for (int es = 0; es < 4; es++) {
            int row = wr * 64 + es * 16 + r;
            int cbyte = (c0 * 2) ^ ((row & 7) << 4);
            uint2 pkd;
            pkd.x = pack2(acc[es][cs][0] + bi.x, acc[es][cs][1] + bi.y);
            pkd.y = pack2(acc[es][cs][2] + bi.z, acc[es][cs][3] + bi.w);
            *(uint2*)((char*)smem + row * 256 + cbyte) = pkd;
        }
    }
    __syncthreads();
    u16* Cg = C + (size_t)gset * NN * 128;
#pragma unroll
    for (int it = 0; it < 8; it++) {
        int idx = it * 256 + t;
        int row = idx >> 4;
        int cb2 = (idx & 15) * 16;
        int swz = cb2 ^ ((row & 7) << 4);
        if (nb + row < NN) {
            uint4 v = *(const uint4*)((const char*)smem + row * 256 + swz);
            *(uint4*)((char*)(Cg + (size_t)(nb + row) * 128) + cb2) = v;
        }
    }
}

// ---------------- Mix MFMA: b = bf16(C0 + amp*C1 + att*C2); + leaky + residual ----------------
// wave = 32 nodes x 128 cols; writes h fp32 AND hb bf16

__global__ __launch_bounds__(256, 3) void mix_mfma(
    const u16* __restrict__ C, const float* __restrict__ amp, const float* __restrict__ att,
    const u16* __restrict__ Wt, const float* __restrict__ bias,
    float* __restrict__ h, u16* __restrict__ hb) {
    int l = threadIdx.x & 63;
    int wid = threadIdx.x >> 6;
    int r = l & 15, g = l >> 4;
    int nbase = blockIdx.x * 128 + wid * 32;
    const u16* C1 = C + (size_t)NN * 128;
    const u16* C2 = C + (size_t)2 * NN * 128;

    int nd[2]; float av[2], tv[2];
#pragma unroll
    for (int es = 0; es < 2; es++) {
        int n2 = nbase + es * 16 + r;
        nd[es] = n2;
        int nc = n2 < NN ? n2 : NN - 1;
        av[es] = amp[nc]; tv[es] = att[nc];
    }

    f32x4 acc[2][8];
#pragma unroll
    for (int es = 0; es < 2; es++)
#pragma unroll
        for (int cs = 0; cs < 8; cs++) acc[es][cs] = (f32x4)(0.f);

#pragma unroll
    for (int ks = 0; ks < 4; ks++) {
        int k0 = ks * 32 + g * 8;
        short8v b[2];
#pragma unroll
        for (int es = 0; es < 2; es++) {
            int nc = nd[es] < NN ? nd[es] : NN - 1;
            size_t off = (size_t)nc * 128 + k0;
            short8v s0 = *(const short8v*)&C[off];
            short8v s1 = *(const short8v*)&C1[off];
            short8v s2 = *(const short8v*)&C2[off];
            float a2 = av[es], t2 = tv[es];
            short8v bbv;
#pragma unroll
            for (int j = 0; j < 8; j++) {
                float v = bf2f((u16)s0[j]) + a2 * bf2f((u16)s1[j]) + t2 * bf2f((u16)s2[j]);
                bbv[j] = (short)f2bf(v);
            }
            b[es] = bbv;
        }
#pragma unroll
        for (int cs = 0; cs < 8; cs++) {
            short8v a = *(const short8v*)(Wt + (size_t)(cs * 16 + r) * 128 + ks * 32 + g * 8);
            acc[0][cs] = __builtin_amdgcn_mfma_f32_16x16x32_bf16(a, b[0], acc[0][cs], 0, 0, 0);
            acc[1][cs] = __builtin_amdgcn_mfma_f32_16x16x32_bf16(a, b[1], acc[1][cs], 0, 0, 0);
        }
    }

#pragma unroll
    for (int cs = 0; cs < 8; cs++) {
        int c0 = cs * 16 + g * 4;
        float4 bi = *(const float4*)&bias[c0];
#pragma unroll
        for (int es = 0; es < 2; es++) {
            if (nd[es] < NN) {
                float4 v;
                v.x = acc[es][cs][0] + bi.x; v.y = acc[es][cs][1] + bi.y;
                v.z = acc[es][cs][2] + bi.z; v.w = acc[es][cs][3] + bi.w;
                v.x = v.x > 0.f ? v.x : 0.01f * v.x;
                v.y = v.y > 0.f ? v.y : 0.01f * v.y;
                v.z = v.z > 0.f ? v.z : 0.01f * v.z;
                v.w = v.w > 0.f ? v.w : 0.01f * v.w;
                size_t idx = (size_t)nd[es] * 128 + c0;
                float4 old = *(const float4*)&h[idx];
                float4 nw;
                nw.x = old.x + v.x; nw.y = old.y + v.y;
                nw.z = old.z + v.z; nw.w = old.w + v.w;
                *(float4*)&h[idx] = nw;
                uint2 pb;
                pb.x = pack2(nw.x, nw.y);
                pb.y = pack2(nw.z, nw.w);
                *(uint2*)&hb[idx] = pb;
            }
        }
    }
}

// ---------------- launch ----------------

extern "C" void kernel_launch(void* const* d_in, const int* in_sizes, int n_in,
                              void* d_out, int out_size, void* d_ws, size_t ws_size,
                              hipStream_t stream) {
    (void)in_sizes; (void)n_in; (void)out_size; (void)ws_size;
    const float* h0    = (const float*)d_in[0];
    const float* efeat = (const float*)d_in[1];
    const int* src     = (const int*)d_in[2];
    const int* dst     = (const int*)d_in[3];
    const float* preW  = (const float*)d_in[4];
    const float* preB  = (const float*)d_in[5];
    const float* postW = (const float*)d_in[6];
    const float* postB = (const float*)d_in[7];
    const float* mixW  = (const float*)d_in[8];
    const float* mixB  = (const float*)d_in[9];
    float* hcur = (float*)d_out;

    char* ws = (char*)d_ws;
    size_t off = 0;
    auto alloc = [&](size_t bytes) {
        void* p = ws + off;
        off += (bytes + 255) & ~(size_t)255;
        return p;
    };
    u16* mbuf    = (u16*)alloc((size_t)EE * 128 * 2);   // 163.84 MB; Cb bf16 (38.4 MB) aliases it
    u16* ebf     = (u16*)alloc((size_t)EE * 64 * 2);    // 81.92 MB
    u16* aggb    = (u16*)alloc((size_t)NN * 512 * 2);   // 51.20 MB
    u16* hb      = (u16*)alloc((size_t)NN * 128 * 2);   // 12.80 MB
    u16* preWt   = (u16*)alloc((size_t)128 * KPRE * 2);
    u16* Wp      = (u16*)alloc((size_t)384 * 640 * 2);
    u16* mixWt   = (u16*)alloc((size_t)128 * 128 * 2);
    int* eid     = (int*)alloc((size_t)EE * 4);
    int* psrc    = (int*)alloc((size_t)EE * 4);
    int* pdst    = (int*)alloc((size_t)EE * 4);
    int* deg     = (int*)alloc((size_t)NN * 4);
    int* rowstart= (int*)alloc((size_t)(NN + 1) * 4);
    int* cursor  = (int*)alloc((size_t)NN * 4);
    float* amp   = (float*)alloc((size_t)NN * 4);
    float* att   = (float*)alloc((size_t)NN * 4);
    u16* Cb      = (u16*)mbuf;   // alias: m dead after agg; Cb dead before next pretrans

    hipMemsetAsync(deg, 0, (size_t)NN * 4, stream);
    hipMemsetAsync(cursor, 0, (size_t)NN * 4, stream);
    hipMemcpyAsync(hcur, h0, (size_t)NN * 128 * 4, hipMemcpyDeviceToDevice, stream);

    deg_kernel<<<(EE + 255) / 256, 256, 0, stream>>>(dst, deg);
    scaler_kernel<<<(NN + 255) / 256, 256, 0, stream>>>(deg, amp, att);
    scan_kernel<<<1, 1024, 0, stream>>>(deg, rowstart);
    fill_kernel<<<(EE + 255) / 256, 256, 0, stream>>>(dst, rowstart, cursor, eid);
    perm_idx_kernel<<<(EE + 255) / 256, 256, 0, stream>>>(eid, src, dst, psrc, pdst);
    cvt_ebf_kernel<<<(EE * 8 + 255) / 256, 256, 0, stream>>>(efeat, eid, ebf);
    cvt_h_kernel<<<(NN * 128 / 4 + 255) / 256, 256, 0, stream>>>(hcur, hb);

    for (int l = 0; l < 2; l++) {
        cvt_wt_kernel<<<(128 * KPRE + 255) / 256, 256, 0, stream>>>(
            preW + (size_t)l * KPRE * 128, preWt, KPRE);
        cvt_wp_kernel<<<(384 * 640 + 255) / 256, 256, 0, stream>>>(
            postW + (size_t)l * 1664 * 128, Wp);
        cvt_wt_kernel<<<(128 * 128 + 255) / 256, 256, 0, stream>>>(
            mixW + (size_t)l * 128 * 128, mixWt, 128);

        pretrans_mfma<<<EE / 128, 256, 0, stream>>>(
            hb, ebf, psrc, pdst, preWt, preB + (size_t)l * 128, mbuf);
        agg_kernel<<<(NN + 3) / 4, 256, 0, stream>>>(mbuf, rowstart, aggb);
        post_mfma<<<dim3((NN + 127) / 128, 3), 256, 0, stream>>>(
            hb, aggb, Wp, postB + (size_t)l * 128, Cb);
        mix_mfma<<<(NN + 127) / 128, 256, 0, stream>>>(
            Cb, amp, att, mixWt, mixB + (size_t)l * 128, hcur, hb);
    }
}